// Round 7
// baseline (276.948 us; speedup 1.0000x reference)
//
#include <hip/hip_runtime.h>

#define NA 50000
#define NB 20000
#define NE0 600000
#define NE1 300000
#define NE2 300000
#define DD 128
#define DEG_TOT (4 * NA + 2 * NB)
#define SUB 32768     // keys per LDS histogram pass (16-bit packed counters, 64 KB)
#define PER 18750     // edges per group: NE0/32 = NE1/16 = NE2/16

// P packed-ushort cell layout (cell = Po[cfg] + g*K + k):
// cfg0 dout0 G=32,K=NA @0        ; cfg1 din0 G=32,K=NA @1600000
// cfg2 dout1 G=16,K=NA @3200000  ; cfg3 din1 G=16,K=NB @4000000
// cfg4 dout2 G=16,K=NB @4320000  ; cfg5 din2 G=16,K=NA @4640000
// O int layout (din offsets): O1 @0 (32*NA) ; O3 @1600000 (16*NB) ; O5 @1920000 (16*NA)

typedef short bf16x8 __attribute__((ext_vector_type(8)));
typedef float f32x4 __attribute__((ext_vector_type(4)));

__device__ __forceinline__ unsigned short f2bf(float f) {
    union { float f; unsigned int u; } v; v.f = f;
    unsigned int r = v.u + 0x7fffu + ((v.u >> 16) & 1u);   // RNE
    return (unsigned short)(r >> 16);
}
__device__ __forceinline__ float lo2f(unsigned int u) {    // low bf16 of dword
    union { float f; unsigned int u; } v; v.u = u << 16;
    return v.f;
}
__device__ __forceinline__ float hi2f(unsigned int u) {    // high bf16 of dword
    union { float f; unsigned int u; } v; v.u = u & 0xffff0000u;
    return v.f;
}

// ---- LDS histograms (z=0..5) + W->bf16 W^T transpose (z=6) ------------------
__global__ __launch_bounds__(1024) void hist_kernel(
    const int* __restrict__ s0, const int* __restrict__ d0,
    const int* __restrict__ s1, const int* __restrict__ d1,
    const int* __restrict__ s2, const int* __restrict__ d2,
    unsigned int* __restrict__ Pd,
    int* __restrict__ rank0, int* __restrict__ rank1, int* __restrict__ rank2,
    const float* __restrict__ W0, const float* __restrict__ W1,
    const float* __restrict__ W2, unsigned short* __restrict__ Wt)
{
    __shared__ unsigned int h32[SUB / 2];
    const int cfg = blockIdx.z;
    if (cfg == 6) {   // Wt[w][c*128+k] = bf16(W_w[k*128+c])
        int flat = blockIdx.y * 2 + blockIdx.x;
        if (flat >= 48) return;
        int i = flat * 1024 + threadIdx.x;
        int w = i >> 14, r = i & (DD * DD - 1);
        int c = r >> 7, k = r & (DD - 1);
        const float* W = (w == 0) ? W0 : ((w == 1) ? W1 : W2);
        Wt[i] = f2bf(W[k * DD + c]);
        return;
    }
    const int En[6] = {NE0, NE0, NE1, NE1, NE2, NE2};
    const int Kn[6] = {NA, NA, NA, NB, NB, NA};
    const int Gn[6] = {32, 32, 16, 16, 16, 16};
    const int Po[6] = {0, 1600000, 3200000, 4000000, 4320000, 4640000};
    int E = En[cfg], K = Kn[cfg], G = Gn[cfg];
    int sub = blockIdx.x, g = blockIdx.y;
    int nsub = (K + SUB - 1) / SUB;
    if (sub >= nsub || g >= G) return;
    const int* keys = cfg == 0 ? s0 : cfg == 1 ? d0 : cfg == 2 ? s1
                    : cfg == 3 ? d1 : cfg == 4 ? s2 : d2;
    int* rk = cfg == 1 ? rank0 : cfg == 3 ? rank1 : cfg == 5 ? rank2 : (int*)0;
    int lo = sub * SUB;
    int hi = min(K, lo + SUB);
    int cnt = hi - lo;
    for (int i = threadIdx.x; i < SUB / 2; i += 1024) h32[i] = 0;
    __syncthreads();
    int e1 = min(E, g * PER + PER);
    for (int e = g * PER + threadIdx.x; e < e1; e += 1024) {
        int k = keys[e];
        if (k >= lo && k < hi) {
            int kk = k - lo;
            unsigned sh = (kk & 1) << 4;
            unsigned old = atomicAdd(&h32[kk >> 1], 1u << sh);
            if (rk) rk[e] = (int)((old >> sh) & 0xffffu);
        }
    }
    __syncthreads();
    unsigned int* outp = Pd + ((Po[cfg] + g * K + lo) >> 1);
    for (int i = threadIdx.x; i < cnt / 2; i += 1024) outp[i] = h32[i];
}

// ---- fused: sum partials -> ideg + rdeg; din regions also emit spart --------
__global__ __launch_bounds__(256) void reduce2(
    const unsigned short* __restrict__ P16, int* __restrict__ ideg,
    float* __restrict__ rdeg, int* __restrict__ spart)
{
    __shared__ int lds[256];
    const int y = blockIdx.y;
    const int Ro[6] = {0, NA, 2 * NA, 3 * NA, 3 * NA + NB, 3 * NA + 2 * NB};
    const int Kr[6] = {NA, NA, NA, NB, NB, NA};
    const int Gr[6] = {32, 32, 16, 16, 16, 16};
    const int Po[6] = {0, 1600000, 3200000, 4000000, 4320000, 4640000};
    int K = Kr[y], G = Gr[y];
    int b = blockIdx.x, t = threadIdx.x;
    if (b * 1024 >= K) return;
    int base = b * 1024 + t * 4;
    int tsum = 0;
    #pragma unroll
    for (int k = 0; k < 4; ++k) {
        int key = base + k;
        if (key < K) {
            const unsigned short* p = P16 + Po[y] + key;
            int s = 0;
            for (int g = 0; g < G; ++g) s += p[g * K];
            ideg[Ro[y] + key] = s;
            rdeg[Ro[y] + key] = rsqrtf(fmaxf((float)s, 1.f));
            tsum += s;
        }
    }
    if (y == 1 || y == 3 || y == 5) {
        int slot = (y - 1) >> 1;
        lds[t] = tsum; __syncthreads();
        for (int o = 128; o > 0; o >>= 1) {
            if (t < o) lds[t] += lds[t + o];
            __syncthreads();
        }
        if (t == 0) spart[slot * 64 + b] = lds[0];
    }
}

// ---- fused: spine + exclusive scan -> rp, and per-(group,key) offsets O -----
__global__ __launch_bounds__(256) void scan_final2(
    const int* __restrict__ ideg, const int* __restrict__ spart,
    const unsigned short* __restrict__ P16,
    int* __restrict__ rp, int* __restrict__ O)
{
    __shared__ int lds[256];
    const int y = blockIdx.y;
    const int off[3]   = {NA, 3 * NA, 3 * NA + 2 * NB};
    const int nn[3]    = {NA, NB, NA};
    const int ro[3]    = {0, NA, NA + NB};
    const int pbase[3] = {1600000, 4000000, 4640000};
    const int obase[3] = {0, 1600000, 1920000};
    const int Gd[3]    = {32, 16, 16};
    int n = nn[y], K = n, G = Gd[y];
    int b = blockIdx.x, t = threadIdx.x;
    if (b * 1024 >= n) return;
    int lane = t & 63;

    // spine: sum of spart entries before block b (wave-redundant butterfly)
    int pv = (lane < b) ? spart[y * 64 + lane] : 0;
    #pragma unroll
    for (int o = 32; o > 0; o >>= 1) pv += __shfl_xor(pv, o);

    const int* deg = ideg + off[y];
    int base = b * 1024 + t * 4;
    int v[4]; int tsum = 0;
    #pragma unroll
    for (int k = 0; k < 4; ++k) {
        v[k] = (base + k < n) ? deg[base + k] : 0;
        tsum += v[k];
    }
    lds[t] = tsum; __syncthreads();
    for (int o = 1; o < 256; o <<= 1) {
        int x = (t >= o) ? lds[t - o] : 0;
        __syncthreads();
        lds[t] += x;
        __syncthreads();
    }
    int run = lds[t] - tsum + pv;
    int* rowptr = rp + ro[y];
    const unsigned short* pb = P16 + pbase[y];
    int* ob = O + obase[y];
    #pragma unroll
    for (int k = 0; k < 4; ++k) {
        int key = base + k;
        if (key < n) {
            rowptr[key] = run;
            int r2 = run;
            for (int g = 0; g < G; ++g) {
                ob[g * K + key] = r2;
                r2 += pb[g * K + key];
            }
            run += v[k];
        }
    }
}

// ---- fully parallel placement: pos = O[g][dst] + rank[e] --------------------
__global__ __launch_bounds__(512) void place_parallel(
    const int* __restrict__ s0, const int* __restrict__ d0,
    const int* __restrict__ s1, const int* __restrict__ d1,
    const int* __restrict__ s2, const int* __restrict__ d2,
    const int* __restrict__ O,
    const int* __restrict__ rank0, const int* __restrict__ rank1,
    const int* __restrict__ rank2,
    int* __restrict__ csr0, int* __restrict__ csr1, int* __restrict__ csr2)
{
    int z = blockIdx.z;
    const int En[3] = {NE0, NE1, NE2};
    const int Kn[3] = {NA, NB, NA};
    const int Oo[3] = {0, 1600000, 1920000};
    int E = En[z], K = Kn[z];
    const int* src = z == 0 ? s0 : z == 1 ? s1 : s2;
    const int* dst = z == 0 ? d0 : z == 1 ? d1 : d2;
    const int* rk  = z == 0 ? rank0 : z == 1 ? rank1 : rank2;
    int* csr = z == 0 ? csr0 : z == 1 ? csr1 : csr2;
    const int* off = O + Oo[z];
    int e = blockIdx.x * 512 + threadIdx.x;
    if (e >= E) return;
    int d = dst[e];
    int g = e / PER;
    int pos = off[g * K + d] + rk[e];
    csr[pos] = src[e];
}

// ---- fused GEMMs: blocks [0,782) dual-W over hA; [782,1095) W2 over hB ------
__global__ __launch_bounds__(256) void gemm_all(
    const float* __restrict__ hA, const float* __restrict__ hB,
    const unsigned short* __restrict__ Wt, const float* __restrict__ rdeg,
    unsigned short* __restrict__ mA0, unsigned short* __restrict__ mA1,
    unsigned short* __restrict__ mB2)
{
    int wid  = threadIdx.x >> 6;
    int lane = threadIdx.x & 63;
    int quad = lane >> 4;
    int l16  = lane & 15;

    if (blockIdx.x < 782) {
        int base = blockIdx.x * 64 + wid * 16;
        if (base >= NA) return;
        int arow = base + l16;
        if (arow >= NA) arow = NA - 1;
        bf16x8 a[4];
        #pragma unroll
        for (int kk = 0; kk < 4; ++kk) {
            const float4* p = (const float4*)(hA + (size_t)arow * DD + kk * 32 + quad * 8);
            float4 u = p[0], w = p[1];
            bf16x8 t;
            t[0] = (short)f2bf(u.x); t[1] = (short)f2bf(u.y);
            t[2] = (short)f2bf(u.z); t[3] = (short)f2bf(u.w);
            t[4] = (short)f2bf(w.x); t[5] = (short)f2bf(w.y);
            t[6] = (short)f2bf(w.z); t[7] = (short)f2bf(w.w);
            a[kk] = t;
        }
        float rs0[4], rs1[4]; int orow0 = base + quad * 4;
        #pragma unroll
        for (int r = 0; r < 4; ++r) {
            int orow = orow0 + r; int c = orow < NA ? orow : 0;
            rs0[r] = rdeg[c]; rs1[r] = rdeg[2 * NA + c];
        }
        #pragma unroll
        for (int ct = 0; ct < 8; ++ct) {
            f32x4 acc0 = {0.f, 0.f, 0.f, 0.f};
            f32x4 acc1 = {0.f, 0.f, 0.f, 0.f};
            const unsigned short* wp = Wt + (size_t)(ct * 16 + l16) * DD + quad * 8;
            #pragma unroll
            for (int kk = 0; kk < 4; ++kk) {
                bf16x8 b0 = *(const bf16x8*)(wp + kk * 32);
                bf16x8 b1 = *(const bf16x8*)(wp + 16384 + kk * 32);
                acc0 = __builtin_amdgcn_mfma_f32_16x16x32_bf16(a[kk], b0, acc0, 0, 0, 0);
                acc1 = __builtin_amdgcn_mfma_f32_16x16x32_bf16(a[kk], b1, acc1, 0, 0, 0);
            }
            #pragma unroll
            for (int r = 0; r < 4; ++r) {
                int orow = orow0 + r;
                if (orow < NA) {
                    mA0[(size_t)orow * DD + ct * 16 + l16] = f2bf(acc0[r] * rs0[r]);
                    mA1[(size_t)orow * DD + ct * 16 + l16] = f2bf(acc1[r] * rs1[r]);
                }
            }
        }
    } else {
        int base = (blockIdx.x - 782) * 64 + wid * 16;
        if (base >= NB) return;
        int arow = base + l16;
        if (arow >= NB) arow = NB - 1;
        bf16x8 a[4];
        #pragma unroll
        for (int kk = 0; kk < 4; ++kk) {
            const float4* p = (const float4*)(hB + (size_t)arow * DD + kk * 32 + quad * 8);
            float4 u = p[0], w = p[1];
            bf16x8 t;
            t[0] = (short)f2bf(u.x); t[1] = (short)f2bf(u.y);
            t[2] = (short)f2bf(u.z); t[3] = (short)f2bf(u.w);
            t[4] = (short)f2bf(w.x); t[5] = (short)f2bf(w.y);
            t[6] = (short)f2bf(w.z); t[7] = (short)f2bf(w.w);
            a[kk] = t;
        }
        float rs[4]; int orow0 = base + quad * 4;
        #pragma unroll
        for (int r = 0; r < 4; ++r) {
            int orow = orow0 + r;
            rs[r] = rdeg[3 * NA + NB + (orow < NB ? orow : 0)];
        }
        #pragma unroll
        for (int ct = 0; ct < 8; ++ct) {
            f32x4 acc = {0.f, 0.f, 0.f, 0.f};
            const unsigned short* wp = Wt + 32768 + (size_t)(ct * 16 + l16) * DD + quad * 8;
            #pragma unroll
            for (int kk = 0; kk < 4; ++kk) {
                bf16x8 b = *(const bf16x8*)(wp + kk * 32);
                acc = __builtin_amdgcn_mfma_f32_16x16x32_bf16(a[kk], b, acc, 0, 0, 0);
            }
            #pragma unroll
            for (int r = 0; r < 4; ++r) {
                int orow = orow0 + r;
                if (orow < NB)
                    mB2[(size_t)orow * DD + ct * 16 + l16] = f2bf(acc[r] * rs[r]);
            }
        }
    }
}

// ---- gather: uint4 loads, 16 lanes/row -> 4 edges per wave instruction ------
// q = lane>>4 selects which edge of the group-of-4; o[8] accumulates 8 bf16
// columns (lane&15)*8 .. +8. Cross-quarter sum happens once in the epilogue.
__device__ __forceinline__ void acc8(float* o, uint4 u) {
    o[0] += lo2f(u.x); o[1] += hi2f(u.x);
    o[2] += lo2f(u.y); o[3] += hi2f(u.y);
    o[4] += lo2f(u.z); o[5] += hi2f(u.z);
    o[6] += lo2f(u.w); o[7] += hi2f(u.w);
}
__device__ __forceinline__ void gather_rel4(
    const char* __restrict__ Mb, const int* __restrict__ csr,
    int st, int n, int lane, int q, unsigned laneoff, float* o)
{
    for (int ch = 0; ch < n; ch += 64) {
        int m = n - ch; if (m > 64) m = 64;
        int idx = csr[st + ch + (lane < m ? lane : m - 1)];  // coalesced prefetch
        int j = 0;
        for (; j + 8 <= m; j += 8) {        // 2 loads in flight, 8 edges/iter
            int sA = __shfl(idx, j + q);
            int sB = __shfl(idx, j + 4 + q);
            uint4 uA = *(const uint4*)(Mb + (((unsigned)sA << 8) + laneoff));
            uint4 uB = *(const uint4*)(Mb + (((unsigned)sB << 8) + laneoff));
            acc8(o, uA); acc8(o, uB);
        }
        if (j + 4 <= m) {
            int s = __shfl(idx, j + q);
            uint4 u = *(const uint4*)(Mb + (((unsigned)s << 8) + laneoff));
            acc8(o, u);
            j += 4;
        }
        if (j < m) {                        // masked tail group
            int jj = j + q;
            float w = jj < m ? 1.f : 0.f;
            int s = __shfl(idx, jj < m ? jj : m - 1);
            uint4 u = *(const uint4*)(Mb + (((unsigned)s << 8) + laneoff));
            o[0] = fmaf(w, lo2f(u.x), o[0]); o[1] = fmaf(w, hi2f(u.x), o[1]);
            o[2] = fmaf(w, lo2f(u.y), o[2]); o[3] = fmaf(w, hi2f(u.y), o[3]);
            o[4] = fmaf(w, lo2f(u.z), o[4]); o[5] = fmaf(w, hi2f(u.z), o[5]);
            o[6] = fmaf(w, lo2f(u.w), o[6]); o[7] = fmaf(w, hi2f(u.w), o[7]);
        }
    }
}

// ---- fused gather: blocks [0,12500) -> out_A rows; [12500,17500) -> out_B ---
__global__ __launch_bounds__(256) void gather_all(
    const unsigned short* __restrict__ mA0, const unsigned short* __restrict__ mA1,
    const unsigned short* __restrict__ mB2,
    const int* __restrict__ csr0, const int* __restrict__ csr1,
    const int* __restrict__ csr2,
    const int* __restrict__ rp, const int* __restrict__ ideg,
    const float* __restrict__ rdeg,
    const float* __restrict__ b0, const float* __restrict__ b1,
    const float* __restrict__ b2,
    float* __restrict__ out)
{
    int wid = threadIdx.x >> 6, lane = threadIdx.x & 63;
    int q = lane >> 4, l16 = lane & 15;
    unsigned laneoff = (unsigned)l16 * 16u;
    float v[8];
    #pragma unroll
    for (int i = 0; i < 8; ++i) v[i] = 0.f;
    float* op;
    const float *bia, *bib;

    if (blockIdx.x < 12500) {
        int d = blockIdx.x * 4 + wid;   // always < NA
        float c[8];
        #pragma unroll
        for (int i = 0; i < 8; ++i) c[i] = 0.f;
        gather_rel4((const char*)mA0, csr0, rp[d], ideg[NA + d], lane, q, laneoff, v);
        gather_rel4((const char*)mB2, csr2, rp[NA + NB + d], ideg[3 * NA + 2 * NB + d],
                    lane, q, laneoff, c);
        float r0 = rdeg[NA + d], r2 = rdeg[3 * NA + 2 * NB + d];
        #pragma unroll
        for (int i = 0; i < 8; ++i) v[i] = v[i] * r0 + c[i] * r2;
        op = out + (size_t)d * DD;
        bia = b0; bib = b2;
    } else {
        int d = (blockIdx.x - 12500) * 4 + wid;   // always < NB
        gather_rel4((const char*)mA1, csr1, rp[NA + d], ideg[3 * NA + d],
                    lane, q, laneoff, v);
        float r1 = rdeg[3 * NA + d];
        #pragma unroll
        for (int i = 0; i < 8; ++i) v[i] *= r1;
        op = out + (size_t)(NA + d) * DD;
        bia = b1; bib = 0;
    }

    // sum the 4 quarters; lanes 0..15 end with cols l16*8..+8
    #pragma unroll
    for (int i = 0; i < 8; ++i) {
        v[i] += __shfl_down(v[i], 32);
        v[i] += __shfl_down(v[i], 16);
    }
    if (lane < 16) {
        int col = l16 * 8;
        float4 ba0 = *(const float4*)(bia + col);
        float4 ba1 = *(const float4*)(bia + col + 4);
        if (bib) {
            float4 bb0 = *(const float4*)(bib + col);
            float4 bb1 = *(const float4*)(bib + col + 4);
            ba0.x += bb0.x; ba0.y += bb0.y; ba0.z += bb0.z; ba0.w += bb0.w;
            ba1.x += bb1.x; ba1.y += bb1.y; ba1.z += bb1.z; ba1.w += bb1.w;
        }
        float4 o0 = {v[0] + ba0.x, v[1] + ba0.y, v[2] + ba0.z, v[3] + ba0.w};
        float4 o1 = {v[4] + ba1.x, v[5] + ba1.y, v[6] + ba1.z, v[7] + ba1.w};
        *(float4*)(op + col) = o0;
        *(float4*)(op + col + 4) = o1;
    }
}

extern "C" void kernel_launch(void* const* d_in, const int* in_sizes, int n_in,
                              void* d_out, int out_size, void* d_ws, size_t ws_size,
                              hipStream_t stream) {
    const float* hA = (const float*)d_in[0];
    const float* hB = (const float*)d_in[1];
    const float* W0 = (const float*)d_in[2];
    const float* b0 = (const float*)d_in[3];
    const float* W1 = (const float*)d_in[4];
    const float* b1 = (const float*)d_in[5];
    const float* W2 = (const float*)d_in[6];
    const float* b2 = (const float*)d_in[7];
    const int* s0 = (const int*)d_in[8];
    const int* d0 = (const int*)d_in[9];
    const int* s1 = (const int*)d_in[10];
    const int* d1 = (const int*)d_in[11];
    const int* s2 = (const int*)d_in[12];
    const int* d2 = (const int*)d_in[13];
    float* out = (float*)d_out;
    char* ws = (char*)d_ws;

    // ws layout. P (10.88 MB packed) + O (10.88 MB) alias mA0/mA1 (dead before gemm).
    unsigned short* mA0 = (unsigned short*)(ws + 0);          // 12.8 MB
    unsigned short* mA1 = (unsigned short*)(ws + 12800000);   // 12.8 MB
    unsigned short* mB2 = (unsigned short*)(ws + 25600000);   // 5.12 MB
    unsigned short* P16 = (unsigned short*)(ws + 0);          // 10.88 MB packed counts
    unsigned int*   Pd  = (unsigned int*)(ws + 0);            // dword view of P16
    int*   O            = (int*)  (ws + 10880000);            // 10.88 MB din offsets
    unsigned short* Wt  = (unsigned short*)(ws + 30720000);   // 96 KB
    float* rdeg         = (float*)(ws + 30818304);            // 960 KB
    int*   ideg         = (int*)  (ws + 31778304);            // 960 KB
    int*   rp           = (int*)  (ws + 32738304);            // 480 KB
    int*   spart        = (int*)  (ws + 33218304);            // 1 KB
    int*   rank0        = (int*)  (ws + 33219328);            // 2.4 MB
    int*   rank1        = (int*)  (ws + 35619328);            // 1.2 MB
    int*   rank2        = (int*)  (ws + 36819328);            // 1.2 MB
    int*   csr0         = (int*)  (ws + 38019328);            // 2.4 MB
    int*   csr1         = (int*)  (ws + 40419328);            // 1.2 MB
    int*   csr2         = (int*)  (ws + 41619328);            // 1.2 MB

    hist_kernel<<<dim3(2, 32, 7), 1024, 0, stream>>>(s0, d0, s1, d1, s2, d2,
        Pd, rank0, rank1, rank2, W0, W1, W2, Wt);
    reduce2<<<dim3(49, 6), 256, 0, stream>>>(P16, ideg, rdeg, spart);
    scan_final2<<<dim3(49, 3), 256, 0, stream>>>(ideg, spart, P16, rp, O);
    place_parallel<<<dim3((NE0 + 511) / 512, 1, 3), 512, 0, stream>>>(
        s0, d0, s1, d1, s2, d2, O, rank0, rank1, rank2, csr0, csr1, csr2);
    gemm_all<<<782 + 313, 256, 0, stream>>>(hA, hB, Wt, rdeg, mA0, mA1, mB2);
    gather_all<<<12500 + 5000, 256, 0, stream>>>(mA0, mA1, mB2,
        csr0, csr1, csr2, rp, ideg, rdeg, b0, b1, b2, out);
}

// Round 8
// 241.732 us; speedup vs baseline: 1.1457x; 1.1457x over previous
//
#include <hip/hip_runtime.h>

#define NA 50000
#define NB 20000
#define NE0 600000
#define NE1 300000
#define NE2 300000
#define DD 128
#define SUB 32768     // keys per LDS histogram pass (16-bit packed counters, 64 KB)
#define PER 18750     // edges per group: NE0/32 = NE1/16 = NE2/16

// P packed-ushort cell layout (cell = Po[cfg] + g*K + k):
// cfg0 dout0 G=32,K=NA @0        ; cfg1 din0 G=32,K=NA @1600000
// cfg2 dout1 G=16,K=NA @3200000  ; cfg3 din1 G=16,K=NB @4000000
// cfg4 dout2 G=16,K=NB @4320000  ; cfg5 din2 G=16,K=NA @4640000
// CUM8 uchar layout: C0 @0 (32*NA) ; C1 @1600000 (16*NB) ; C2 @1920000 (16*NA)

typedef short bf16x8 __attribute__((ext_vector_type(8)));
typedef float f32x4 __attribute__((ext_vector_type(4)));

__device__ __forceinline__ unsigned short f2bf(float f) {
    union { float f; unsigned int u; } v; v.f = f;
    unsigned int r = v.u + 0x7fffu + ((v.u >> 16) & 1u);   // RNE
    return (unsigned short)(r >> 16);
}
__device__ __forceinline__ float lo2f(unsigned int u) {
    union { float f; unsigned int u; } v; v.u = u << 16;
    return v.f;
}
__device__ __forceinline__ float hi2f(unsigned int u) {
    union { float f; unsigned int u; } v; v.u = u & 0xffff0000u;
    return v.f;
}

// ---- LDS histograms (z=0..5) + W->bf16 W^T transpose (z=6) ------------------
__global__ __launch_bounds__(1024) void hist_kernel(
    const int* __restrict__ s0, const int* __restrict__ d0,
    const int* __restrict__ s1, const int* __restrict__ d1,
    const int* __restrict__ s2, const int* __restrict__ d2,
    unsigned int* __restrict__ Pd,
    unsigned char* __restrict__ rank0, unsigned char* __restrict__ rank1,
    unsigned char* __restrict__ rank2,
    const float* __restrict__ W0, const float* __restrict__ W1,
    const float* __restrict__ W2, unsigned short* __restrict__ Wt)
{
    __shared__ unsigned int h32[SUB / 2];
    const int cfg = blockIdx.z;
    if (cfg == 6) {   // Wt[w][c*128+k] = bf16(W_w[k*128+c])
        int flat = blockIdx.y * 2 + blockIdx.x;
        if (flat >= 48) return;
        int i = flat * 1024 + threadIdx.x;
        int w = i >> 14, r = i & (DD * DD - 1);
        int c = r >> 7, k = r & (DD - 1);
        const float* W = (w == 0) ? W0 : ((w == 1) ? W1 : W2);
        Wt[i] = f2bf(W[k * DD + c]);
        return;
    }
    const int En[6] = {NE0, NE0, NE1, NE1, NE2, NE2};
    const int Kn[6] = {NA, NA, NA, NB, NB, NA};
    const int Gn[6] = {32, 32, 16, 16, 16, 16};
    const int Po[6] = {0, 1600000, 3200000, 4000000, 4320000, 4640000};
    int E = En[cfg], K = Kn[cfg], G = Gn[cfg];
    int sub = blockIdx.x, g = blockIdx.y;
    int nsub = (K + SUB - 1) / SUB;
    if (sub >= nsub || g >= G) return;
    const int* keys = cfg == 0 ? s0 : cfg == 1 ? d0 : cfg == 2 ? s1
                    : cfg == 3 ? d1 : cfg == 4 ? s2 : d2;
    unsigned char* rk = cfg == 1 ? rank0 : cfg == 3 ? rank1
                      : cfg == 5 ? rank2 : (unsigned char*)0;
    int lo = sub * SUB;
    int hi = min(K, lo + SUB);
    int cnt = hi - lo;
    for (int i = threadIdx.x; i < SUB / 2; i += 1024) h32[i] = 0;
    __syncthreads();
    int e1 = min(E, g * PER + PER);
    for (int e = g * PER + threadIdx.x; e < e1; e += 1024) {
        int k = keys[e];
        if (k >= lo && k < hi) {
            int kk = k - lo;
            unsigned sh = (kk & 1) << 4;
            unsigned old = atomicAdd(&h32[kk >> 1], 1u << sh);
            if (rk) rk[e] = (unsigned char)((old >> sh) & 0xffu);
        }
    }
    __syncthreads();
    unsigned int* outp = Pd + ((Po[cfg] + g * K + lo) >> 1);
    for (int i = threadIdx.x; i < cnt / 2; i += 1024) outp[i] = h32[i];
}

// ---- fused: partial sums -> ideg/rdeg; din cfgs also emit CUM8 + spart ------
// 1 key per thread, fully coalesced. spart granularity: 256-key chunks.
__global__ __launch_bounds__(256) void reduce2(
    const unsigned short* __restrict__ P16, int* __restrict__ ideg,
    float* __restrict__ rdeg, int* __restrict__ spart,
    unsigned char* __restrict__ cum8)
{
    __shared__ int lds[256];
    const int y = blockIdx.y;
    const int Ro[6] = {0, NA, 2 * NA, 3 * NA, 3 * NA + NB, 3 * NA + 2 * NB};
    const int Kr[6] = {NA, NA, NA, NB, NB, NA};
    const int Gr[6] = {32, 32, 16, 16, 16, 16};
    const int Po[6] = {0, 1600000, 3200000, 4000000, 4320000, 4640000};
    const int Co[6] = {0, 0, 0, 1600000, 0, 1920000};
    int K = Kr[y], G = Gr[y];
    int b = blockIdx.x, t = threadIdx.x;
    int nchunk = (K + 255) >> 8;
    if (b >= nchunk) return;
    int key = b * 256 + t;
    bool valid = key < K;
    bool din = (y == 1) || (y == 3) || (y == 5);
    const unsigned short* p = P16 + Po[y] + key;
    unsigned char* cb = cum8 + Co[y] + key;
    int run = 0;
    for (int g = 0; g < G; ++g) {
        if (din && valid) cb[g * K] = (unsigned char)run;
        run += valid ? p[g * K] : 0;
    }
    if (valid) {
        ideg[Ro[y] + key] = run;
        rdeg[Ro[y] + key] = rsqrtf(fmaxf((float)run, 1.f));
    }
    if (din) {
        int slot = (y - 1) >> 1;
        lds[t] = run; __syncthreads();
        for (int o = 128; o > 0; o >>= 1) {
            if (t < o) lds[t] += lds[t + o];
            __syncthreads();
        }
        if (t == 0) spart[slot * 256 + b] = lds[0];
    }
}

// ---- rowptr scan: spine over 256-key spart chunks + block-local scan --------
__global__ __launch_bounds__(256) void scan3(
    const int* __restrict__ ideg, const int* __restrict__ spart,
    int* __restrict__ rp)
{
    __shared__ int lds[256];
    const int y = blockIdx.y;
    const int off[3] = {NA, 3 * NA, 3 * NA + 2 * NB};
    const int nn[3]  = {NA, NB, NA};
    const int ro[3]  = {0, NA, NA + NB};
    int n = nn[y];
    int b = blockIdx.x, t = threadIdx.x;
    if (b * 1024 >= n) return;

    // base = sum of spart chunks [0, 4b)
    lds[t] = (t < 4 * b) ? spart[y * 256 + t] : 0;
    __syncthreads();
    for (int o = 128; o > 0; o >>= 1) {
        if (t < o) lds[t] += lds[t + o];
        __syncthreads();
    }
    int pv = lds[0];
    __syncthreads();

    const int* deg = ideg + off[y];
    int base = b * 1024 + t * 4;
    int v[4]; int tsum = 0;
    #pragma unroll
    for (int k = 0; k < 4; ++k) {
        v[k] = (base + k < n) ? deg[base + k] : 0;
        tsum += v[k];
    }
    lds[t] = tsum; __syncthreads();
    for (int o = 1; o < 256; o <<= 1) {
        int x = (t >= o) ? lds[t - o] : 0;
        __syncthreads();
        lds[t] += x;
        __syncthreads();
    }
    int run = lds[t] - tsum + pv;
    int* rowptr = rp + ro[y];
    #pragma unroll
    for (int k = 0; k < 4; ++k) {
        if (base + k < n) rowptr[base + k] = run;
        run += v[k];
    }
}

// ---- fused work: placement (blocks 0..2343) + MFMA GEMMs (2344..2891) -------
// place: pos = rp[d] + CUM8[g*K+d] + rank8[e]   (no global atomics)
__global__ __launch_bounds__(512) void work_kernel(
    const int* __restrict__ s0, const int* __restrict__ d0,
    const int* __restrict__ s1, const int* __restrict__ d1,
    const int* __restrict__ s2, const int* __restrict__ d2,
    const unsigned char* __restrict__ cum8,
    const unsigned char* __restrict__ rank0, const unsigned char* __restrict__ rank1,
    const unsigned char* __restrict__ rank2,
    const int* __restrict__ rp,
    int* __restrict__ csr0, int* __restrict__ csr1, int* __restrict__ csr2,
    const float* __restrict__ hA, const float* __restrict__ hB,
    const unsigned short* __restrict__ Wt, const float* __restrict__ rdeg,
    unsigned short* __restrict__ mA0, unsigned short* __restrict__ mA1,
    unsigned short* __restrict__ mB2)
{
    int bx = blockIdx.x;
    if (bx < 2344) {   // ---- placement ----
        int z = (bx < 1172) ? 0 : (bx < 1758) ? 1 : 2;
        const int zb[3] = {0, 1172, 1758};
        const int En[3] = {NE0, NE1, NE2};
        const int Kn[3] = {NA, NB, NA};
        const int Co[3] = {0, 1600000, 1920000};
        const int ro[3] = {0, NA, NA + NB};
        int E = En[z], K = Kn[z];
        const int* src = z == 0 ? s0 : z == 1 ? s1 : s2;
        const int* dst = z == 0 ? d0 : z == 1 ? d1 : d2;
        const unsigned char* rk = z == 0 ? rank0 : z == 1 ? rank1 : rank2;
        int* csr = z == 0 ? csr0 : z == 1 ? csr1 : csr2;
        int e = (bx - zb[z]) * 512 + threadIdx.x;
        if (e >= E) return;
        int d = dst[e];
        int g = e / PER;
        int pos = rp[ro[z] + d] + (int)cum8[Co[z] + g * K + d] + (int)rk[e];
        csr[pos] = src[e];
        return;
    }
    // ---- GEMMs: 8 waves x 16 rows = 128 rows / block ----
    int wid  = threadIdx.x >> 6;
    int lane = threadIdx.x & 63;
    int quad = lane >> 4;
    int l16  = lane & 15;
    if (bx < 2344 + 391) {   // dual-W over hA
        int base = (bx - 2344) * 128 + wid * 16;
        if (base >= NA) return;
        int arow = base + l16;
        if (arow >= NA) arow = NA - 1;
        bf16x8 a[4];
        #pragma unroll
        for (int kk = 0; kk < 4; ++kk) {
            const float4* p = (const float4*)(hA + (size_t)arow * DD + kk * 32 + quad * 8);
            float4 u = p[0], w = p[1];
            bf16x8 t;
            t[0] = (short)f2bf(u.x); t[1] = (short)f2bf(u.y);
            t[2] = (short)f2bf(u.z); t[3] = (short)f2bf(u.w);
            t[4] = (short)f2bf(w.x); t[5] = (short)f2bf(w.y);
            t[6] = (short)f2bf(w.z); t[7] = (short)f2bf(w.w);
            a[kk] = t;
        }
        float rs0[4], rs1[4]; int orow0 = base + quad * 4;
        #pragma unroll
        for (int r = 0; r < 4; ++r) {
            int orow = orow0 + r; int c = orow < NA ? orow : 0;
            rs0[r] = rdeg[c]; rs1[r] = rdeg[2 * NA + c];
        }
        #pragma unroll
        for (int ct = 0; ct < 8; ++ct) {
            f32x4 acc0 = {0.f, 0.f, 0.f, 0.f};
            f32x4 acc1 = {0.f, 0.f, 0.f, 0.f};
            const unsigned short* wp = Wt + (size_t)(ct * 16 + l16) * DD + quad * 8;
            #pragma unroll
            for (int kk = 0; kk < 4; ++kk) {
                bf16x8 b0 = *(const bf16x8*)(wp + kk * 32);
                bf16x8 b1 = *(const bf16x8*)(wp + 16384 + kk * 32);
                acc0 = __builtin_amdgcn_mfma_f32_16x16x32_bf16(a[kk], b0, acc0, 0, 0, 0);
                acc1 = __builtin_amdgcn_mfma_f32_16x16x32_bf16(a[kk], b1, acc1, 0, 0, 0);
            }
            #pragma unroll
            for (int r = 0; r < 4; ++r) {
                int orow = orow0 + r;
                if (orow < NA) {
                    mA0[(size_t)orow * DD + ct * 16 + l16] = f2bf(acc0[r] * rs0[r]);
                    mA1[(size_t)orow * DD + ct * 16 + l16] = f2bf(acc1[r] * rs1[r]);
                }
            }
        }
    } else {   // W2 over hB
        int base = (bx - 2735) * 128 + wid * 16;
        if (base >= NB) return;
        int arow = base + l16;
        if (arow >= NB) arow = NB - 1;
        bf16x8 a[4];
        #pragma unroll
        for (int kk = 0; kk < 4; ++kk) {
            const float4* p = (const float4*)(hB + (size_t)arow * DD + kk * 32 + quad * 8);
            float4 u = p[0], w = p[1];
            bf16x8 t;
            t[0] = (short)f2bf(u.x); t[1] = (short)f2bf(u.y);
            t[2] = (short)f2bf(u.z); t[3] = (short)f2bf(u.w);
            t[4] = (short)f2bf(w.x); t[5] = (short)f2bf(w.y);
            t[6] = (short)f2bf(w.z); t[7] = (short)f2bf(w.w);
            a[kk] = t;
        }
        float rs[4]; int orow0 = base + quad * 4;
        #pragma unroll
        for (int r = 0; r < 4; ++r) {
            int orow = orow0 + r;
            rs[r] = rdeg[3 * NA + NB + (orow < NB ? orow : 0)];
        }
        #pragma unroll
        for (int ct = 0; ct < 8; ++ct) {
            f32x4 acc = {0.f, 0.f, 0.f, 0.f};
            const unsigned short* wp = Wt + 32768 + (size_t)(ct * 16 + l16) * DD + quad * 8;
            #pragma unroll
            for (int kk = 0; kk < 4; ++kk) {
                bf16x8 b = *(const bf16x8*)(wp + kk * 32);
                acc = __builtin_amdgcn_mfma_f32_16x16x32_bf16(a[kk], b, acc, 0, 0, 0);
            }
            #pragma unroll
            for (int r = 0; r < 4; ++r) {
                int orow = orow0 + r;
                if (orow < NB)
                    mB2[(size_t)orow * DD + ct * 16 + l16] = f2bf(acc[r] * rs[r]);
            }
        }
    }
}

// ---- gather: uint4 loads, 16 lanes/row -> 4 edges per wave instruction ------
__device__ __forceinline__ void acc8(float* o, uint4 u) {
    o[0] += lo2f(u.x); o[1] += hi2f(u.x);
    o[2] += lo2f(u.y); o[3] += hi2f(u.y);
    o[4] += lo2f(u.z); o[5] += hi2f(u.z);
    o[6] += lo2f(u.w); o[7] += hi2f(u.w);
}
__device__ __forceinline__ void gather_rel4(
    const char* __restrict__ Mb, const int* __restrict__ csr,
    int st, int n, int lane, int q, unsigned laneoff, float* o)
{
    for (int ch = 0; ch < n; ch += 64) {
        int m = n - ch; if (m > 64) m = 64;
        int idx = csr[st + ch + (lane < m ? lane : m - 1)];  // coalesced prefetch
        int j = 0;
        for (; j + 8 <= m; j += 8) {        // 2 loads in flight, 8 edges/iter
            int sA = __shfl(idx, j + q);
            int sB = __shfl(idx, j + 4 + q);
            uint4 uA = *(const uint4*)(Mb + (((unsigned)sA << 8) + laneoff));
            uint4 uB = *(const uint4*)(Mb + (((unsigned)sB << 8) + laneoff));
            acc8(o, uA); acc8(o, uB);
        }
        if (j + 4 <= m) {
            int s = __shfl(idx, j + q);
            uint4 u = *(const uint4*)(Mb + (((unsigned)s << 8) + laneoff));
            acc8(o, u);
            j += 4;
        }
        if (j < m) {                        // masked tail group
            int jj = j + q;
            float w = jj < m ? 1.f : 0.f;
            int s = __shfl(idx, jj < m ? jj : m - 1);
            uint4 u = *(const uint4*)(Mb + (((unsigned)s << 8) + laneoff));
            o[0] = fmaf(w, lo2f(u.x), o[0]); o[1] = fmaf(w, hi2f(u.x), o[1]);
            o[2] = fmaf(w, lo2f(u.y), o[2]); o[3] = fmaf(w, hi2f(u.y), o[3]);
            o[4] = fmaf(w, lo2f(u.z), o[4]); o[5] = fmaf(w, hi2f(u.z), o[5]);
            o[6] = fmaf(w, lo2f(u.w), o[6]); o[7] = fmaf(w, hi2f(u.w), o[7]);
        }
    }
}

// ---- fused gather: blocks [0,12500) -> out_A rows; [12500,17500) -> out_B ---
__global__ __launch_bounds__(256) void gather_all(
    const unsigned short* __restrict__ mA0, const unsigned short* __restrict__ mA1,
    const unsigned short* __restrict__ mB2,
    const int* __restrict__ csr0, const int* __restrict__ csr1,
    const int* __restrict__ csr2,
    const int* __restrict__ rp, const int* __restrict__ ideg,
    const float* __restrict__ rdeg,
    const float* __restrict__ b0, const float* __restrict__ b1,
    const float* __restrict__ b2,
    float* __restrict__ out)
{
    int wid = threadIdx.x >> 6, lane = threadIdx.x & 63;
    int q = lane >> 4, l16 = lane & 15;
    unsigned laneoff = (unsigned)l16 * 16u;
    float v[8];
    #pragma unroll
    for (int i = 0; i < 8; ++i) v[i] = 0.f;
    float* op;
    const float *bia, *bib;

    if (blockIdx.x < 12500) {
        int d = blockIdx.x * 4 + wid;   // always < NA
        float c[8];
        #pragma unroll
        for (int i = 0; i < 8; ++i) c[i] = 0.f;
        gather_rel4((const char*)mA0, csr0, rp[d], ideg[NA + d], lane, q, laneoff, v);
        gather_rel4((const char*)mB2, csr2, rp[NA + NB + d], ideg[3 * NA + 2 * NB + d],
                    lane, q, laneoff, c);
        float r0 = rdeg[NA + d], r2 = rdeg[3 * NA + 2 * NB + d];
        #pragma unroll
        for (int i = 0; i < 8; ++i) v[i] = v[i] * r0 + c[i] * r2;
        op = out + (size_t)d * DD;
        bia = b0; bib = b2;
    } else {
        int d = (blockIdx.x - 12500) * 4 + wid;   // always < NB
        gather_rel4((const char*)mA1, csr1, rp[NA + d], ideg[3 * NA + d],
                    lane, q, laneoff, v);
        float r1 = rdeg[3 * NA + d];
        #pragma unroll
        for (int i = 0; i < 8; ++i) v[i] *= r1;
        op = out + (size_t)(NA + d) * DD;
        bia = b1; bib = 0;
    }

    #pragma unroll
    for (int i = 0; i < 8; ++i) {
        v[i] += __shfl_down(v[i], 32);
        v[i] += __shfl_down(v[i], 16);
    }
    if (lane < 16) {
        int col = l16 * 8;
        float4 ba0 = *(const float4*)(bia + col);
        float4 ba1 = *(const float4*)(bia + col + 4);
        if (bib) {
            float4 bb0 = *(const float4*)(bib + col);
            float4 bb1 = *(const float4*)(bib + col + 4);
            ba0.x += bb0.x; ba0.y += bb0.y; ba0.z += bb0.z; ba0.w += bb0.w;
            ba1.x += bb1.x; ba1.y += bb1.y; ba1.z += bb1.z; ba1.w += bb1.w;
        }
        float4 o0 = {v[0] + ba0.x, v[1] + ba0.y, v[2] + ba0.z, v[3] + ba0.w};
        float4 o1 = {v[4] + ba1.x, v[5] + ba1.y, v[6] + ba1.z, v[7] + ba1.w};
        *(float4*)(op + col) = o0;
        *(float4*)(op + col + 4) = o1;
    }
}

extern "C" void kernel_launch(void* const* d_in, const int* in_sizes, int n_in,
                              void* d_out, int out_size, void* d_ws, size_t ws_size,
                              hipStream_t stream) {
    const float* hA = (const float*)d_in[0];
    const float* hB = (const float*)d_in[1];
    const float* W0 = (const float*)d_in[2];
    const float* b0 = (const float*)d_in[3];
    const float* W1 = (const float*)d_in[4];
    const float* b1 = (const float*)d_in[5];
    const float* W2 = (const float*)d_in[6];
    const float* b2 = (const float*)d_in[7];
    const int* s0 = (const int*)d_in[8];
    const int* d0 = (const int*)d_in[9];
    const int* s1 = (const int*)d_in[10];
    const int* d1 = (const int*)d_in[11];
    const int* s2 = (const int*)d_in[12];
    const int* d2 = (const int*)d_in[13];
    float* out = (float*)d_out;
    char* ws = (char*)d_ws;

    // ws layout. P16 (10.88 MB packed) aliases mA0 (dead before work_kernel's gemm).
    unsigned short* mA0 = (unsigned short*)(ws + 0);          // 12.8 MB
    unsigned short* mA1 = (unsigned short*)(ws + 12800000);   // 12.8 MB
    unsigned short* mB2 = (unsigned short*)(ws + 25600000);   // 5.12 MB
    unsigned short* P16 = (unsigned short*)(ws + 0);          // 10.88 MB packed counts
    unsigned int*   Pd  = (unsigned int*)(ws + 0);            // dword view of P16
    unsigned short* Wt  = (unsigned short*)(ws + 30720000);   // 96 KB
    float* rdeg         = (float*)(ws + 30818304);            // 960 KB
    int*   ideg         = (int*)  (ws + 31778304);            // 960 KB
    int*   rp           = (int*)  (ws + 32738304);            // 480 KB
    int*   spart        = (int*)  (ws + 33218304);            // 3 KB
    unsigned char* cum8 = (unsigned char*)(ws + 33221376);    // 2.72 MB
    unsigned char* rank0= (unsigned char*)(ws + 35941376);    // 600 KB
    unsigned char* rank1= (unsigned char*)(ws + 36541376);    // 300 KB
    unsigned char* rank2= (unsigned char*)(ws + 36841376);    // 300 KB
    int*   csr0         = (int*)  (ws + 37141376);            // 2.4 MB
    int*   csr1         = (int*)  (ws + 39541376);            // 1.2 MB
    int*   csr2         = (int*)  (ws + 40741376);            // 1.2 MB

    hist_kernel<<<dim3(2, 32, 7), 1024, 0, stream>>>(s0, d0, s1, d1, s2, d2,
        Pd, rank0, rank1, rank2, W0, W1, W2, Wt);
    reduce2<<<dim3(196, 6), 256, 0, stream>>>(P16, ideg, rdeg, spart, cum8);
    scan3<<<dim3(49, 3), 256, 0, stream>>>(ideg, spart, rp);
    work_kernel<<<2892, 512, 0, stream>>>(s0, d0, s1, d1, s2, d2,
        cum8, rank0, rank1, rank2, rp, csr0, csr1, csr2,
        hA, hB, Wt, rdeg, mA0, mA1, mB2);
    gather_all<<<12500 + 5000, 256, 0, stream>>>(mA0, mA1, mB2,
        csr0, csr1, csr2, rp, ideg, rdeg, b0, b1, b2, out);
}